// Round 6
// baseline (114.873 us; speedup 1.0000x reference)
//
#include <hip/hip_runtime.h>

typedef unsigned short us;
typedef __attribute__((ext_vector_type(8))) short short8;
typedef __attribute__((ext_vector_type(4))) float f32x4;

__device__ __forceinline__ us f2bf(float f) {
  unsigned int u = __builtin_bit_cast(unsigned int, f);
  u += 0x7fffu + ((u >> 16) & 1u);
  return (us)(u >> 16);
}

// 16B-wide async global->LDS DMA. LDS dest = wave-uniform base + lane*16.
__device__ __forceinline__ void gload_lds16(const void* g, void* l) {
  __builtin_amdgcn_global_load_lds(
      (const __attribute__((address_space(1))) void*)g,
      (__attribute__((address_space(3))) void*)l, 16, 0, 0);
}

// ---- prep: entity k-split GEMM (256, first) + token cast (4096) + Wt transpose (256) ----
__global__ __launch_bounds__(256) void prep_kernel(
    const float* __restrict__ token, us* __restrict__ tokb,
    const float* __restrict__ Wt, us* __restrict__ WtT,
    const float* __restrict__ entity, const float* __restrict__ We,
    float* __restrict__ epart) {
  __shared__ float tile[64][65];
  __shared__ float eS[16][128];
  const int bid = blockIdx.x, tid = threadIdx.x;
  if (bid < 256) {  // entity k-split partial GEMM, coalesced We reads
    int kc = bid & 7, nt = (bid >> 3) & 7, b = bid >> 6;
    int k0 = kc << 7, n0 = nt << 7;
#pragma unroll
    for (int p = 0; p < 2; ++p) {
      int idx = (p << 8) + tid;
      int r = idx >> 5, kk = (idx & 31) << 2;
      *(float4*)&eS[r][kk] = *(const float4*)&entity[(size_t)(((b << 4) + r) << 10) + k0 + kk];
    }
    __syncthreads();
    const int col = tid & 127, rh = tid >> 7;
    const float* wP = We + ((size_t)k0 << 10) + n0 + col;
    float acc[8] = {0.f, 0.f, 0.f, 0.f, 0.f, 0.f, 0.f, 0.f};
#pragma unroll 8
    for (int k = 0; k < 128; ++k) {
      float wv = wP[(size_t)k << 10];
#pragma unroll
      for (int r = 0; r < 8; ++r)
        acc[r] = fmaf(wv, eS[(rh << 3) + r][k], acc[r]);
    }
    float* op = epart + (((size_t)((kc << 6) + (b << 4) + (rh << 3))) << 10) + n0 + col;
#pragma unroll
    for (int r = 0; r < 8; ++r) op[(size_t)r << 10] = acc[r];
  } else if (bid < 4352) {  // token f32 -> bf16
    int q = (bid - 256) * 256 + tid;
    float4 v = ((const float4*)token)[q];
    ushort4 o;
    o.x = f2bf(v.x); o.y = f2bf(v.y); o.z = f2bf(v.z); o.w = f2bf(v.w);
    ((ushort4*)tokb)[q] = o;
  } else {  // Wt[k][n] -> WtT[n][k] bf16
    int tb = bid - 4352;
    int bx = (tb & 15) << 6, by = ((tb >> 4) & 15) << 6;
    int r0 = tid >> 4, c0 = (tid & 15) << 2;
#pragma unroll
    for (int p = 0; p < 4; ++p) {
      int r = p * 16 + r0;
      float4 v = *(const float4*)&Wt[(size_t)(by + r) * 1024 + bx + c0];
      tile[r][c0] = v.x; tile[r][c0 + 1] = v.y;
      tile[r][c0 + 2] = v.z; tile[r][c0 + 3] = v.w;
    }
    __syncthreads();
#pragma unroll
    for (int p = 0; p < 4; ++p) {
      int r = p * 16 + r0;
      ushort4 o;
      o.x = f2bf(tile[c0 + 0][r]); o.y = f2bf(tile[c0 + 1][r]);
      o.z = f2bf(tile[c0 + 2][r]); o.w = f2bf(tile[c0 + 3][r]);
      *(ushort4*)&WtT[(size_t)(bx + r) * 1024 + by + c0] = o;
    }
  }
}

// ---- main: transposed token GEMM (C[h,t]) + fused relu-dot epilogue ----
// Tile 128h x 64t, grid (8 mh, 64 tt). Depth-3 pipeline: triple-buffer LDS,
// steady-state s_waitcnt vmcnt(6) (retire tile kt, keep kt+1/kt+2 in flight).
__global__ __launch_bounds__(256) void main_kernel(
    const us* __restrict__ tokb, const us* __restrict__ WtT,
    const float* __restrict__ epart, const float* __restrict__ be,
    const float* __restrict__ bt, const float* __restrict__ wp,
    float* __restrict__ partial) {
  __shared__ __attribute__((aligned(16))) us Ws[3][4096];  // 128h x 32k per buf
  __shared__ __attribute__((aligned(16))) us Ts[3][2048];  // 64t x 32k per buf
  __shared__ __attribute__((aligned(16))) float eL[16][132];
  __shared__ __attribute__((aligned(16))) float btL[128];
  __shared__ __attribute__((aligned(16))) float wpL[128];
  __shared__ float pp[2][64][9];
  const int tid = threadIdx.x;
  const int mh = blockIdx.x, tt = blockIdx.y;
  const int h0 = mh << 7, b = tt >> 4, t0 = (tt & 15) << 6;
  // staging pointers; issue prologue DMAs FIRST (overlap with phase-1 reads)
  const int row1 = tid >> 2, kc4 = (tid & 3) << 3;
  const us* wP = WtT + (size_t)(h0 + row1) * 1024 + kc4;
  const us* tP = tokb + (size_t)((b << 10) + t0 + row1) * 1024 + kc4;
  const int w = tid >> 6;
  us* wB[3] = {&Ws[0][w * 512], &Ws[1][w * 512], &Ws[2][w * 512]};
  us* tB[3] = {&Ts[0][w * 512], &Ts[1][w * 512], &Ts[2][w * 512]};
#pragma unroll
  for (int j = 0; j < 3; ++j) {  // tiles 0,1,2 -> bufs 0,1,2 (9 DMAs, tile-order)
    gload_lds16(wP + (j << 5), wB[j]);
    gload_lds16(wP + 65536 + (j << 5), wB[j] + 2048);
    gload_lds16(tP + (j << 5), tB[j]);
  }
  // phase 1: entity act = sum of 8 k-partials + be -> eL; bt, wp -> LDS
#pragma unroll
  for (int p = 0; p < 2; ++p) {
    int q = (p << 8) + tid;
    int er = q >> 5, ec = (q & 31) << 2;
    f32x4 s = *(const f32x4*)&be[h0 + ec];
#pragma unroll
    for (int kc = 0; kc < 8; ++kc)
      s += *(const f32x4*)&epart[(((size_t)((kc << 6) + (b << 4) + er)) << 10) + h0 + ec];
    *(f32x4*)&eL[er][ec] = s;
  }
  if (tid < 128) btL[tid] = bt[h0 + tid];
  else wpL[tid - 128] = wp[h0 + tid - 128];
  asm volatile("" ::: "memory");
  const int lane = tid & 63, wm = (tid >> 7) & 1, wn = (tid >> 6) & 1;
  const int l16 = lane & 15, oct = lane >> 4, ko = oct << 3;
  int wfo[4], tfo[2];
#pragma unroll
  for (int i = 0; i < 4; ++i) wfo[i] = (((wm << 6) + (i << 4) + l16) << 5) + ko;
#pragma unroll
  for (int j = 0; j < 2; ++j) tfo[j] = (((wn << 5) + (j << 4) + l16) << 5) + ko;
  f32x4 acc[4][2] = {};
  // K-loop body: wait(tile kt) / barrier / MFMA / barrier / prefetch kt+3
#define KBODY(KT, BUF, VMC, ISSUE)                                              \
  {                                                                             \
    __builtin_amdgcn_s_waitcnt(VMC);                                            \
    __builtin_amdgcn_s_barrier();                                               \
    asm volatile("" ::: "memory");                                              \
    short8 af[4], bfr[2];                                                       \
    _Pragma("unroll") for (int i = 0; i < 4; ++i)                               \
        af[i] = *(const short8*)&Ws[BUF][wfo[i]];                               \
    _Pragma("unroll") for (int j = 0; j < 2; ++j)                               \
        bfr[j] = *(const short8*)&Ts[BUF][tfo[j]];                              \
    _Pragma("unroll") for (int i = 0; i < 4; ++i)                               \
        _Pragma("unroll") for (int j = 0; j < 2; ++j)                           \
            acc[i][j] = __builtin_amdgcn_mfma_f32_16x16x32_bf16(                \
                af[i], bfr[j], acc[i][j], 0, 0, 0);                             \
    asm volatile("" ::: "memory");                                              \
    if (ISSUE) {                                                                \
      __builtin_amdgcn_s_barrier();                                             \
      int nk = (KT) + 3; if (nk > 31) nk = 31; /* dummy keeps counts uniform */ \
      int ko2 = nk << 5;                                                        \
      gload_lds16(wP + ko2, wB[BUF]);                                           \
      gload_lds16(wP + 65536 + ko2, wB[BUF] + 2048);                            \
      gload_lds16(tP + ko2, tB[BUF]);                                           \
    }                                                                           \
  }
  for (int g = 0; g < 10; ++g) {  // kt = 3g, 3g+1, 3g+2  (0..29)
    int kt = g * 3;
    KBODY(kt + 0, 0, 0x0f76, 1);
    KBODY(kt + 1, 1, 0x0f76, 1);
    KBODY(kt + 2, 2, 0x0f76, 1);
  }
  KBODY(30, 0, 0x0f76, 0);  // outstanding 9 -> wait 6: tile30 landed
  KBODY(31, 1, 0x0f73, 0);  // outstanding 6 -> wait 3: tile31 landed (dummies fly)
#undef KBODY
  // ---- fused epilogue: per e, p[t] = sum_h relu(acc + bt + e) * Wp ----
  f32x4 btq[4], wpq[4];
#pragma unroll
  for (int i = 0; i < 4; ++i) {
    int hb = (wm << 6) + (i << 4) + (oct << 2);
    btq[i] = *(const f32x4*)&btL[hb];
    wpq[i] = *(const f32x4*)&wpL[hb];
  }
#pragma unroll
  for (int i = 0; i < 4; ++i)
#pragma unroll
    for (int j = 0; j < 2; ++j) acc[i][j] += btq[i];
  for (int eh = 0; eh < 2; ++eh) {  // two halves of 8 entities (pp halved)
    __syncthreads();
#pragma unroll
    for (int e8 = 0; e8 < 8; ++e8) {
      int e = (eh << 3) + e8;
      f32x4 ev[4];
#pragma unroll
      for (int i = 0; i < 4; ++i)
        ev[i] = *(const f32x4*)&eL[e][(wm << 6) + (i << 4) + (oct << 2)];
      float pj[2] = {0.f, 0.f};
#pragma unroll
      for (int j = 0; j < 2; ++j)
#pragma unroll
        for (int i = 0; i < 4; ++i)
#pragma unroll
          for (int r = 0; r < 4; ++r)
            pj[j] = fmaf(fmaxf(acc[i][j][r] + ev[i][r], 0.f), wpq[i][r], pj[j]);
#pragma unroll
      for (int j = 0; j < 2; ++j) {
        pj[j] += __shfl_xor(pj[j], 16, 64);
        pj[j] += __shfl_xor(pj[j], 32, 64);
      }
      if (oct == 0) {
#pragma unroll
        for (int j = 0; j < 2; ++j) pp[wm][(wn << 5) + (j << 4) + l16][e8] = pj[j];
      }
    }
    __syncthreads();
#pragma unroll
    for (int q = 0; q < 2; ++q) {
      int flat = (q << 8) + tid;          // 0..511 = e8*64 + tl
      int e8 = flat >> 6, tl = flat & 63;
      float v = pp[0][tl][e8] + pp[1][tl][e8];
      partial[((size_t)mh << 16) +
              (size_t)((((b << 4) + (eh << 3) + e8) << 10) + t0 + tl)] = v;
    }
  }
}

// ---- finalize: sum 8 h-tile partials + bp, mask, sigmoid ----
__global__ __launch_bounds__(256) void finalize_kernel(
    const float* __restrict__ partial, const float* __restrict__ bp,
    const int* __restrict__ mask, float* __restrict__ out) {
  int idx = blockIdx.x * 256 + threadIdx.x;  // (b*16+e)*1024 + t
  float s = 0.f;
#pragma unroll
  for (int mh = 0; mh < 8; ++mh) s += partial[((size_t)mh << 16) + idx];
  float cls = s + bp[0];
  int b = idx >> 14, t = idx & 1023;
  if (mask[(b << 10) + t] == 0) cls = -10000.0f;
  float p = 1.0f / (1.0f + __expf(-cls));
  out[idx] = cls;
  out[65536 + idx] = p;
}

extern "C" void kernel_launch(void* const* d_in, const int* in_sizes, int n_in,
                              void* d_out, int out_size, void* d_ws, size_t ws_size,
                              hipStream_t stream) {
  const float* token = (const float*)d_in[0];
  const float* entity = (const float*)d_in[1];
  const int* mask = (const int*)d_in[2];
  const float* Wt = (const float*)d_in[3];
  const float* bt = (const float*)d_in[4];
  const float* We = (const float*)d_in[5];
  const float* be = (const float*)d_in[6];
  const float* Wp = (const float*)d_in[7];
  const float* bp = (const float*)d_in[8];
  float* out = (float*)d_out;

  char* ws = (char*)d_ws;
  us* tokb = (us*)ws;                                   // 8 MB
  us* WtT = tokb + (size_t)4096 * 1024;                 // 2 MB
  float* epart = (float*)(WtT + (size_t)1024 * 1024);   // 2 MB [8][64][1024]
  float* partial = epart + (size_t)8 * 64 * 1024;       // 2 MB [8][4*16*1024]

  prep_kernel<<<4608, 256, 0, stream>>>(token, tokb, Wt, WtT, entity, We, epart);
  main_kernel<<<dim3(8, 64), 256, 0, stream>>>(tokb, WtT, epart, be, bt, Wp, partial);
  finalize_kernel<<<256, 256, 0, stream>>>(partial, bp, mask, out);
}